// Round 7
// baseline (1013.391 us; speedup 1.0000x reference)
//
#include <hip/hip_runtime.h>
#include <hip/hip_fp16.h>

// ---------------------------------------------------------------------------
// EdgeClassifierGNN: 2x SAGEConv(mean)+BN+ReLU, then 3-layer edge MLP.
// Trick 1: lin_l before mean-aggregation (64-wide gather).
// Trick 2: edge-MLP layer 1 split: z1 = relu(u[src] + v[dst] + B1*attr).
// Trick 3: CSR by dst -> atomic-free aggregation.
// Trick 4: node linears via register-blocked GEMM, BN fused on input.
// Trick 5 (r7): ALL random-gather tables in fp16 (q: 6.4 MB, u: 12.8 MB) and
//          k_edge iterates in dst-CSR order so v[dst] streams from cache.
//          Round-6 evidence: k_edge + k_agg are bound on L2-miss gather bytes.
// ---------------------------------------------------------------------------

#define EPS 1e-5f

// ---------------- CSR build ----------------
__global__ __launch_bounds__(256) void k_hist(
    const int* __restrict__ dst, int* __restrict__ deg, int E) {
  int e = blockIdx.x * 256 + threadIdx.x;
  if (e < E) atomicAdd(&deg[dst[e]], 1);
}

__global__ __launch_bounds__(1024) void k_scan(
    const int* __restrict__ deg, int* __restrict__ rowptr,
    int* __restrict__ cursor, int N) {
  __shared__ int wsum[16];
  __shared__ int carry;
  const int lane = threadIdx.x & 63;
  const int w    = threadIdx.x >> 6;
  if (threadIdx.x == 0) carry = 0;
  __syncthreads();
  for (int base = 0; base < N; base += 1024) {
    int i = base + threadIdx.x;
    int v = (i < N) ? deg[i] : 0;
    int incl = v;
#pragma unroll
    for (int off = 1; off < 64; off <<= 1) {
      int t = __shfl_up(incl, off);
      if (lane >= off) incl += t;
    }
    if (lane == 63) wsum[w] = incl;
    __syncthreads();
    if (w == 0) {
      int ws_ = (lane < 16) ? wsum[lane] : 0;
      int wincl = ws_;
#pragma unroll
      for (int off = 1; off < 16; off <<= 1) {
        int t = __shfl_up(wincl, off);
        if (lane >= off) wincl += t;
      }
      if (lane < 16) wsum[lane] = wincl;
    }
    __syncthreads();
    int woff = carry + (w > 0 ? wsum[w - 1] : 0);
    int excl = woff + incl - v;
    if (i < N) { rowptr[i] = excl; cursor[i] = excl; }
    int tot = wsum[15];
    __syncthreads();
    if (threadIdx.x == 0) carry += tot;
    __syncthreads();
  }
  if (threadIdx.x == 0) rowptr[N] = carry;
}

__global__ __launch_bounds__(256) void k_fill(
    const int* __restrict__ src, const int* __restrict__ dst,
    int* __restrict__ cursor, int* __restrict__ csr_src,
    int* __restrict__ csr_dst, int* __restrict__ csr_eid, int E) {
  int e = blockIdx.x * 256 + threadIdx.x;
  if (e < E) {
    int d = dst[e];
    int pos = atomicAdd(&cursor[d], 1);
    csr_src[pos] = src[e];
    csr_dst[pos] = d;
    csr_eid[pos] = e;
  }
}

// ---------------- weight prep (k-major concatenated layouts) ----------------
__global__ __launch_bounds__(256) void k_prep(
    const float* __restrict__ W1l, const float* __restrict__ W1r,
    const float* __restrict__ b1l,
    const float* __restrict__ W2l, const float* __restrict__ W2r,
    const float* __restrict__ b2l,
    const float* __restrict__ Wm1, const float* __restrict__ bm1,
    const float* __restrict__ Wm2,
    float* __restrict__ Wt1, float* __restrict__ Wt2, float* __restrict__ Wt3,
    float* __restrict__ bias1, float* __restrict__ bias2,
    float* __restrict__ bias3, float* __restrict__ BT,
    __half2* __restrict__ W2h) {
  int idx = blockIdx.x * 256 + threadIdx.x;
  if (idx < 16384) {  // Wt1 [128k x 128f] = [W1l | W1r]^T
    int k = idx >> 7, f = idx & 127;
    Wt1[idx] = (f < 64) ? W1l[f * 128 + k] : W1r[(f - 64) * 128 + k];
    return;
  }
  idx -= 16384;
  if (idx < 8192) {   // Wt2 [64k x 128f] = [W2l | W2r]^T
    int k = idx >> 7, f = idx & 127;
    Wt2[idx] = (f < 64) ? W2l[f * 64 + k] : W2r[(f - 64) * 64 + k];
    return;
  }
  idx -= 8192;
  if (idx < 16384) {  // Wt3 [64k x 256f] = [A1 | C1]^T  (col slices of Wm1)
    int k = idx >> 8, f = idx & 255;
    Wt3[idx] = (f < 128) ? Wm1[f * 144 + k] : Wm1[(f - 128) * 144 + 80 + k];
    return;
  }
  idx -= 16384;
  if (idx < 128) { bias1[idx] = (idx < 64) ? 0.f : b1l[idx - 64]; return; }
  idx -= 128;
  if (idx < 128) { bias2[idx] = (idx < 64) ? 0.f : b2l[idx - 64]; return; }
  idx -= 128;
  if (idx < 256) { bias3[idx] = (idx < 128) ? bm1[idx] : 0.f; return; }
  idx -= 256;
  if (idx < 2048) {   // BT [16k x 128c] = attr-slice of Wm1, fp32
    int k = idx >> 7, c = idx & 127;
    BT[idx] = Wm1[c * 144 + 64 + k];
    return;
  }
  idx -= 2048;
  if (idx < 4096) {   // W2h [128k x 32 half2] = Wm2^T in fp16
    int k = idx >> 5, fp = idx & 31;
    W2h[idx] = __floats2half2_rn(Wm2[(2 * fp) * 128 + k],
                                 Wm2[(2 * fp + 1) * 128 + k]);
    return;
  }
}

// ---------------- register-blocked node GEMM ----------------
// acc[n][f] = bias[f] + sum_k Xeff[n][k] * Wt[k*Ftot+f], f in [0,128)
// Xeff = stats ? relu(X*sc+sh) : X.  Tile 64n x 128f, BK=32, 4x8 acc/thread.
// MODE 0 (conv): cols 0-63 -> half outH (stride 64), 64-127 -> float outF (stride 64)
// MODE 1: all 128 cols -> half outH (stride 128)
// MODE 2: all 128 cols -> float outF (stride 128)
template<int K, int MODE>
__global__ __launch_bounds__(256) void k_gemm(
    const float* __restrict__ X, const float* __restrict__ stats,
    const float* __restrict__ Wt, const float* __restrict__ bias,
    __half* __restrict__ outH, float* __restrict__ outF, int N, int Ftot) {
  __shared__ __align__(16) float Xs[32][68];
  __shared__ __align__(16) float Ws_[32][128];
  const int tid = threadIdx.x;
  const int tx  = tid & 15;   // 8 feats [8tx..)
  const int ty  = tid >> 4;   // 4 nodes [4ty..)
  const int n0  = blockIdx.x * 64;
  float acc[4][8];
#pragma unroll
  for (int j = 0; j < 8; ++j) {
    float bv = bias[8 * tx + j];
#pragma unroll
    for (int i = 0; i < 4; ++i) acc[i][j] = bv;
  }
  for (int k0 = 0; k0 < K; k0 += 32) {
    __syncthreads();
#pragma unroll
    for (int l = 0; l < 2; ++l) {
      int idx = tid * 2 + l;
      int kq = idx & 7, n = idx >> 3;
      float4 xv = make_float4(0.f, 0.f, 0.f, 0.f);
      if (n0 + n < N) xv = *(const float4*)&X[(size_t)(n0 + n) * K + k0 + kq * 4];
      if (stats) {
        int kb = k0 + kq * 4;
        xv.x = fmaxf(xv.x * stats[128 + kb + 0] + stats[192 + kb + 0], 0.f);
        xv.y = fmaxf(xv.y * stats[128 + kb + 1] + stats[192 + kb + 1], 0.f);
        xv.z = fmaxf(xv.z * stats[128 + kb + 2] + stats[192 + kb + 2], 0.f);
        xv.w = fmaxf(xv.w * stats[128 + kb + 3] + stats[192 + kb + 3], 0.f);
      }
      Xs[kq * 4 + 0][n] = xv.x;
      Xs[kq * 4 + 1][n] = xv.y;
      Xs[kq * 4 + 2][n] = xv.z;
      Xs[kq * 4 + 3][n] = xv.w;
    }
#pragma unroll
    for (int l = 0; l < 4; ++l) {
      int idx = tid + l * 256;
      int kr = idx >> 5, fc = idx & 31;
      *(float4*)&Ws_[kr][fc * 4] =
          *(const float4*)&Wt[(size_t)(k0 + kr) * Ftot + fc * 4];
    }
    __syncthreads();
#pragma unroll
    for (int kk = 0; kk < 32; ++kk) {
      float4 a  = *(const float4*)&Xs[kk][4 * ty];
      float4 b0 = *(const float4*)&Ws_[kk][8 * tx];
      float4 b1 = *(const float4*)&Ws_[kk][8 * tx + 4];
      float aa[4] = {a.x, a.y, a.z, a.w};
      float bb[8] = {b0.x, b0.y, b0.z, b0.w, b1.x, b1.y, b1.z, b1.w};
#pragma unroll
      for (int i = 0; i < 4; ++i)
#pragma unroll
        for (int j = 0; j < 8; ++j) acc[i][j] += aa[i] * bb[j];
    }
  }
#pragma unroll
  for (int i = 0; i < 4; ++i) {
    int n = n0 + 4 * ty + i;
    if (n >= N) continue;
    if constexpr (MODE == 0) {
      if (tx < 8) {       // q half, cols 8tx..8tx+7 of [0,64)
        __half2 hh[4];
#pragma unroll
        for (int c = 0; c < 4; ++c)
          hh[c] = __floats2half2_rn(acc[i][2 * c], acc[i][2 * c + 1]);
        *(uint4*)&outH[(size_t)n * 64 + 8 * tx] = *(uint4*)hh;
      } else {            // p float, cols 8tx-64..
        float* cp = outF + (size_t)n * 64 + 8 * tx - 64;
        *(float4*)cp = make_float4(acc[i][0], acc[i][1], acc[i][2], acc[i][3]);
        *(float4*)(cp + 4) = make_float4(acc[i][4], acc[i][5], acc[i][6], acc[i][7]);
      }
    } else if constexpr (MODE == 1) {
      __half2 hh[4];
#pragma unroll
      for (int c = 0; c < 4; ++c)
        hh[c] = __floats2half2_rn(acc[i][2 * c], acc[i][2 * c + 1]);
      *(uint4*)&outH[(size_t)n * 128 + 8 * tx] = *(uint4*)hh;
    } else {
      float* cp = outF + (size_t)n * 128 + 8 * tx;
      *(float4*)cp = make_float4(acc[i][0], acc[i][1], acc[i][2], acc[i][3]);
      *(float4*)(cp + 4) = make_float4(acc[i][4], acc[i][5], acc[i][6], acc[i][7]);
    }
  }
}

// ---------------- fused aggregate + mean + residual + BN stats ----------------
// hpre[n][f] = (sum_{j in row n} q16[csr[j]*64+f]) / max(deg,1) + p[n*64+f]
__global__ __launch_bounds__(256) void k_agg(
    const __half* __restrict__ qb, const float* __restrict__ pb,
    const int* __restrict__ rowptr, const int* __restrict__ csr_src,
    float* __restrict__ hpre, float* __restrict__ stats, int N) {
  __shared__ float red[512];
  const int f  = threadIdx.x & 63;
  const int ns = threadIdx.x >> 6;
  float lsum = 0.f, lsq = 0.f;
  for (int n = blockIdx.x * 4 + ns; n < N; n += gridDim.x * 4) {
    const int r0 = rowptr[n], r1 = rowptr[n + 1];
    float s0 = 0.f, s1 = 0.f, s2 = 0.f, s3 = 0.f;
    int j = r0;
    for (; j + 3 < r1; j += 4) {
      int a0 = csr_src[j], a1 = csr_src[j + 1];
      int a2 = csr_src[j + 2], a3 = csr_src[j + 3];
      s0 += __half2float(qb[(size_t)a0 * 64 + f]);
      s1 += __half2float(qb[(size_t)a1 * 64 + f]);
      s2 += __half2float(qb[(size_t)a2 * 64 + f]);
      s3 += __half2float(qb[(size_t)a3 * 64 + f]);
    }
    for (; j < r1; ++j) s0 += __half2float(qb[(size_t)csr_src[j] * 64 + f]);
    float c = (float)(r1 - r0);
    c = c > 1.f ? c : 1.f;
    float v = ((s0 + s1) + (s2 + s3)) / c + pb[(size_t)n * 64 + f];
    hpre[(size_t)n * 64 + f] = v;
    lsum += v;
    lsq  += v * v;
  }
  red[threadIdx.x]       = lsum;
  red[256 + threadIdx.x] = lsq;
  __syncthreads();
  if (threadIdx.x < 64) {
    float ts = red[f] + red[f + 64] + red[f + 128] + red[f + 192];
    float tq = red[256 + f] + red[256 + f + 64] + red[256 + f + 128] + red[256 + f + 192];
    atomicAdd(&stats[f], ts);
    atomicAdd(&stats[64 + f], tq);
  }
}

// stats -> BN scale/shift: sc=g*invstd, sh=be-mean*sc
__global__ void k_finalize(float* stats, const float* __restrict__ g,
                           const float* __restrict__ be, int N) {
  int f = threadIdx.x;  // 64 threads
  float inv_n = 1.0f / (float)N;
  float mean = stats[f] * inv_n;
  float var  = stats[64 + f] * inv_n - mean * mean;
  float s = g[f] * rsqrtf(var + EPS);
  stats[128 + f] = s;
  stats[192 + f] = be[f] - mean * s;
}

// ---------------------------------------------------------------------------
// Fused edge MLP, dst-CSR edge order. Per 64-edge tile:
//   z1[e][c] = relu(u16[csrc[e]][c] + v[cdst[e]][c] + attr[ceid[e]]·BT[:,c])
//   z2 = relu(z1 @ W2T + bm2) (fp16 LDS, fp32 accum)
//   out[ceid[e]] = z2 @ Wm3.T + bm3 (fused via LDS atomics)
// u random fp16 (256 B/edge), v streams (dst sorted), attr/out scatter by eid.
// LDS ~= 38 KB -> 4 blocks/CU.
// ---------------------------------------------------------------------------
__global__ __launch_bounds__(256, 4) void k_edge(
    const __half* __restrict__ U16, const float* __restrict__ V32,
    const float* __restrict__ attr,
    const int* __restrict__ csrc, const int* __restrict__ cdst,
    const int* __restrict__ ceid,
    const __half2* __restrict__ W2hws, const float* __restrict__ BTws,
    const float* __restrict__ bm2, const float* __restrict__ Wm3,
    const float* __restrict__ bm3, float* __restrict__ out, int E) {
  __shared__ __align__(16) __half2 W2h[128 * 32];  // 16 KB
  __shared__ __align__(16) __half2 Z1h[64 * 66];   // 16.5 KB
  __shared__ __align__(16) float attrL[64 * 16];   // 4 KB
  __shared__ int   idxL[128];                      // src | dst
  __shared__ int   eidL[64];
  __shared__ float outT[128];

  const int tid = threadIdx.x;
  const int c4  = tid & 31;
  const int tx  = tid & 15;
  const int ty  = tid >> 4;

  for (int i = tid; i < 1024; i += 256)
    ((uint4*)W2h)[i] = ((const uint4*)W2hws)[i];

  const __half2* uh2 = (const __half2*)U16;  // 64 half2 per node row
  const float4*  v4  = (const float4*)V32;   // 32 float4 per node row
  const float4*  at4 = (const float4*)attr;
  const float4*  bt4 = (const float4*)BTws;

  const int nt = (E + 63) >> 6;
  for (int t = blockIdx.x; t < nt; t += gridDim.x) {
    const int e0 = t << 6;
    __syncthreads();   // protect LDS vs previous iteration (incl. W2h staging)

    if (tid < 64) {
      int j = e0 + tid;
      idxL[tid]      = (j < E) ? csrc[j] : 0;
      idxL[64 + tid] = (j < E) ? cdst[j] : 0;
      eidL[tid]      = (j < E) ? ceid[j] : -1;
    }
    if (tid < 128) outT[tid] = bm3[tid & 1];
    float4 breg[16];
#pragma unroll
    for (int k = 0; k < 16; ++k) breg[k] = bt4[k * 32 + c4];
    __syncthreads();

    {  // attr gather by original edge id
      int e = tid >> 2, k4 = tid & 3;
      int eid = eidL[e];
      float4 av = make_float4(0.f, 0.f, 0.f, 0.f);
      if (eid >= 0) av = at4[(size_t)eid * 4 + k4];
      ((float4*)attrL)[tid] = av;
    }
    __syncthreads();

    // ---- layer 1: 64 edges x 32 col-chunks of 4, fp16 u + fp32 v ----
#pragma unroll
    for (int it = 0; it < 8; ++it) {
      const int e = it * 8 + (tid >> 5);
      uint2 ur = *(const uint2*)&uh2[(size_t)idxL[e] * 64 + 2 * c4];
      float2 u01 = __half22float2(*reinterpret_cast<__half2*>(&ur.x));
      float2 u23 = __half22float2(*reinterpret_cast<__half2*>(&ur.y));
      float4 b = v4[(size_t)idxL[64 + e] * 32 + c4];
      float sx = u01.x + b.x, sy = u01.y + b.y;
      float sz = u23.x + b.z, sw = u23.y + b.w;
#pragma unroll
      for (int k = 0; k < 16; ++k) {
        float av = attrL[e * 16 + k];
        sx += av * breg[k].x; sy += av * breg[k].y;
        sz += av * breg[k].z; sw += av * breg[k].w;
      }
      Z1h[e * 66 + 2 * c4]     = __floats2half2_rn(fmaxf(sx, 0.f), fmaxf(sy, 0.f));
      Z1h[e * 66 + 2 * c4 + 1] = __floats2half2_rn(fmaxf(sz, 0.f), fmaxf(sw, 0.f));
    }
    __syncthreads();

    // ---- layer 2: [64e x 64c], K=128, 4x4/thread, fp16 loads fp32 math ----
    float acc[4][4];
#pragma unroll
    for (int c = 0; c < 4; ++c) {
      float bv = bm2[4 * tx + c];
#pragma unroll
      for (int i = 0; i < 4; ++i) acc[i][c] = bv;
    }
    for (int kk = 0; kk < 128; kk += 4) {
      float aa[4][4], bb[4][4];
#pragma unroll
      for (int i = 0; i < 4; ++i) {
        uint2 ra = *reinterpret_cast<const uint2*>(&Z1h[(4 * ty + i) * 66 + (kk >> 1)]);
        float2 lo = __half22float2(*reinterpret_cast<__half2*>(&ra.x));
        float2 hi = __half22float2(*reinterpret_cast<__half2*>(&ra.y));
        aa[i][0] = lo.x; aa[i][1] = lo.y; aa[i][2] = hi.x; aa[i][3] = hi.y;
      }
#pragma unroll
      for (int q = 0; q < 4; ++q) {
        uint2 rb = *reinterpret_cast<const uint2*>(&W2h[(kk + q) * 32 + 2 * tx]);
        float2 lo = __half22float2(*reinterpret_cast<__half2*>(&rb.x));
        float2 hi = __half22float2(*reinterpret_cast<__half2*>(&rb.y));
        bb[q][0] = lo.x; bb[q][1] = lo.y; bb[q][2] = hi.x; bb[q][3] = hi.y;
      }
#pragma unroll
      for (int i = 0; i < 4; ++i)
#pragma unroll
        for (int q = 0; q < 4; ++q)
#pragma unroll
          for (int c = 0; c < 4; ++c) acc[i][c] += aa[i][q] * bb[q][c];
    }

    // ---- fused layer 3 ----
    float w30[4], w31[4];
#pragma unroll
    for (int c = 0; c < 4; ++c) {
      w30[c] = Wm3[4 * tx + c];
      w31[c] = Wm3[64 + 4 * tx + c];
    }
#pragma unroll
    for (int i = 0; i < 4; ++i) {
      float p0 = 0.f, p1 = 0.f;
#pragma unroll
      for (int c = 0; c < 4; ++c) {
        float z = fmaxf(acc[i][c], 0.f);
        p0 += z * w30[c];
        p1 += z * w31[c];
      }
      atomicAdd(&outT[(4 * ty + i) * 2 + 0], p0);
      atomicAdd(&outT[(4 * ty + i) * 2 + 1], p1);
    }
    __syncthreads();

    if (tid < 128) {
      int e = tid >> 1;
      int eid = eidL[e];
      if (eid >= 0) out[(size_t)eid * 2 + (tid & 1)] = outT[tid];
    }
  }
}

extern "C" void kernel_launch(void* const* d_in, const int* in_sizes, int n_in,
                              void* d_out, int out_size, void* d_ws, size_t ws_size,
                              hipStream_t stream) {
  const float* x    = (const float*)d_in[0];
  const int*   ei   = (const int*)d_in[1];
  const float* attr = (const float*)d_in[2];
  const float* W1l  = (const float*)d_in[3];
  const float* b1l  = (const float*)d_in[4];
  const float* W1r  = (const float*)d_in[5];
  const float* g1   = (const float*)d_in[6];
  const float* be1  = (const float*)d_in[7];
  const float* W2l  = (const float*)d_in[8];
  const float* b2l  = (const float*)d_in[9];
  const float* W2r  = (const float*)d_in[10];
  const float* g2   = (const float*)d_in[11];
  const float* be2  = (const float*)d_in[12];
  const float* Wm1  = (const float*)d_in[13];
  const float* bm1  = (const float*)d_in[14];
  const float* Wm2  = (const float*)d_in[15];
  const float* bm2  = (const float*)d_in[16];
  const float* Wm3  = (const float*)d_in[17];
  const float* bm3  = (const float*)d_in[18];
  float* out = (float*)d_out;

  const int N = in_sizes[0] / 128;
  const int E = in_sizes[1] / 2;
  const int* srcI = ei;
  const int* dstI = ei + E;

  float* ws = (float*)d_ws;
  const size_t NF = (size_t)N * 64;
  float*  P32 = ws;                        // [N][64] f32
  float*  H1  = ws + NF;                   // [N][64] f32 (reused as H2)
  float*  V32 = ws + 2 * NF;               // [N][128] f32
  __half* Q16 = (__half*)(ws + 4 * NF);    // [N][64] f16  (NF/2 floats)
  __half* U16 = (__half*)(ws + 4 * NF + NF / 2);  // [N][128] f16 (NF floats)
  float* small  = ws + 5 * NF + NF / 2;
  float* stats1 = small;          // 256
  float* stats2 = stats1 + 256;   // 256
  float* Wt1    = stats2 + 256;   // 128*128
  float* Wt2    = Wt1 + 16384;    // 64*128
  float* Wt3    = Wt2 + 8192;     // 64*256
  float* bias1  = Wt3 + 16384;    // 128
  float* bias2  = bias1 + 128;    // 128
  float* bias3  = bias2 + 128;    // 256
  float* BTws   = bias3 + 256;    // 16*128
  __half2* W2h  = (__half2*)(BTws + 2048);  // 4096 half2 = 4096 floats
  int* rowptr = (int*)(BTws + 2048 + 4096); // N+1
  int* cursor = rowptr + (N + 1);           // N
  int* deg    = cursor + N;                 // N
  int* csrsrc = deg + N;                    // E
  int* csrdst = csrsrc + E;                 // E
  int* csreid = csrdst + E;                 // E

  hipMemsetAsync(deg, 0, (size_t)N * sizeof(int), stream);
  hipMemsetAsync(stats1, 0, 512 * sizeof(float), stream);

  // ---- CSR build + weight prep ----
  const int eBlocks = (E + 255) / 256;
  k_hist<<<eBlocks, 256, 0, stream>>>(dstI, deg, E);
  k_scan<<<1, 1024, 0, stream>>>(deg, rowptr, cursor, N);
  k_fill<<<eBlocks, 256, 0, stream>>>(srcI, dstI, cursor, csrsrc, csrdst, csreid, E);
  k_prep<<<(47616 + 255) / 256, 256, 0, stream>>>(
      W1l, W1r, b1l, W2l, W2r, b2l, Wm1, bm1, Wm2,
      Wt1, Wt2, Wt3, bias1, bias2, bias3, BTws, W2h);

  const int mTiles = (N + 63) / 64;

  // ---- conv1: Q16 = fp16(x@W1l^T), P32 = x@W1r^T + b1l ----
  k_gemm<128, 0><<<mTiles, 256, 0, stream>>>(x, nullptr, Wt1, bias1, Q16, P32, N, 128);
  k_agg<<<1024, 256, 0, stream>>>(Q16, P32, rowptr, csrsrc, H1, stats1, N);
  k_finalize<<<1, 64, 0, stream>>>(stats1, g1, be1, N);

  // ---- conv2 (BN1+relu fused into GEMM input) ----
  k_gemm<64, 0><<<mTiles, 256, 0, stream>>>(H1, stats1, Wt2, bias2, Q16, P32, N, 128);
  k_agg<<<1024, 256, 0, stream>>>(Q16, P32, rowptr, csrsrc, H1, stats2, N);  // H2=H1
  k_finalize<<<1, 64, 0, stream>>>(stats2, g2, be2, N);

  // ---- U16 = fp16(h2@A1^T + bm1), V32 = h2@C1^T (BN2+relu fused) ----
  k_gemm<64, 1><<<mTiles, 256, 0, stream>>>(H1, stats2, Wt3, bias3, U16, nullptr, N, 256);
  k_gemm<64, 2><<<mTiles, 256, 0, stream>>>(H1, stats2, Wt3 + 128, bias3 + 128,
                                            nullptr, V32, N, 256);

  // ---- fused edge MLP over dst-ordered edges ----
  k_edge<<<1024, 256, 0, stream>>>(U16, V32, attr, csrsrc, csrdst, csreid,
                                   W2h, BTws, bm2, Wm3, bm3, out, E);
}

// Round 8
// 691.067 us; speedup vs baseline: 1.4664x; 1.4664x over previous
//
#include <hip/hip_runtime.h>
#include <hip/hip_fp16.h>

// ---------------------------------------------------------------------------
// EdgeClassifierGNN: 2x SAGEConv(mean)+BN+ReLU, then 3-layer edge MLP.
// Trick 1: lin_l before mean-aggregation (64-wide gather).
// Trick 2: edge-MLP layer 1 split: z1 = relu(u[src] + v[dst] + B1*attr).
// Trick 3: CSR by dst -> atomic-free aggregation; k_edge in dst order.
// Trick 4: node linears via register-blocked GEMM, BN fused on input.
// Trick 5: random-gather tables in fp16 (q 6.4 MB, u 12.8 MB).
// Trick 6 (r8): k_edge layer 2 via v_mfma_f32_16x16x32_f16 (Z1 fp16 in LDS,
//          W2 pre-swizzled to B-fragment layout). Layer 3 from C-layout accs
//          with shfl_xor reduce + direct stores (outT atomics deleted).
//          Round-7 evidence: k_edge VALU-issue-bound, 75% of slots in layer 2.
// ---------------------------------------------------------------------------

#define EPS 1e-5f

typedef _Float16 h8 __attribute__((ext_vector_type(8)));
typedef float f32x4 __attribute__((ext_vector_type(4)));

// ---------------- CSR build ----------------
__global__ __launch_bounds__(256) void k_hist(
    const int* __restrict__ dst, int* __restrict__ deg, int E) {
  int e = blockIdx.x * 256 + threadIdx.x;
  if (e < E) atomicAdd(&deg[dst[e]], 1);
}

__global__ __launch_bounds__(1024) void k_scan(
    const int* __restrict__ deg, int* __restrict__ rowptr,
    int* __restrict__ cursor, int N) {
  __shared__ int wsum[16];
  __shared__ int carry;
  const int lane = threadIdx.x & 63;
  const int w    = threadIdx.x >> 6;
  if (threadIdx.x == 0) carry = 0;
  __syncthreads();
  for (int base = 0; base < N; base += 1024) {
    int i = base + threadIdx.x;
    int v = (i < N) ? deg[i] : 0;
    int incl = v;
#pragma unroll
    for (int off = 1; off < 64; off <<= 1) {
      int t = __shfl_up(incl, off);
      if (lane >= off) incl += t;
    }
    if (lane == 63) wsum[w] = incl;
    __syncthreads();
    if (w == 0) {
      int ws_ = (lane < 16) ? wsum[lane] : 0;
      int wincl = ws_;
#pragma unroll
      for (int off = 1; off < 16; off <<= 1) {
        int t = __shfl_up(wincl, off);
        if (lane >= off) wincl += t;
      }
      if (lane < 16) wsum[lane] = wincl;
    }
    __syncthreads();
    int woff = carry + (w > 0 ? wsum[w - 1] : 0);
    int excl = woff + incl - v;
    if (i < N) { rowptr[i] = excl; cursor[i] = excl; }
    int tot = wsum[15];
    __syncthreads();
    if (threadIdx.x == 0) carry += tot;
    __syncthreads();
  }
  if (threadIdx.x == 0) rowptr[N] = carry;
}

__global__ __launch_bounds__(256) void k_fill(
    const int* __restrict__ src, const int* __restrict__ dst,
    int* __restrict__ cursor, int* __restrict__ csr_src,
    int* __restrict__ csr_dst, int* __restrict__ csr_eid, int E) {
  int e = blockIdx.x * 256 + threadIdx.x;
  if (e < E) {
    int d = dst[e];
    int pos = atomicAdd(&cursor[d], 1);
    csr_src[pos] = src[e];
    csr_dst[pos] = d;
    csr_eid[pos] = e;
  }
}

// ---------------- weight prep (k-major concatenated layouts) ----------------
__global__ __launch_bounds__(256) void k_prep(
    const float* __restrict__ W1l, const float* __restrict__ W1r,
    const float* __restrict__ b1l,
    const float* __restrict__ W2l, const float* __restrict__ W2r,
    const float* __restrict__ b2l,
    const float* __restrict__ Wm1, const float* __restrict__ bm1,
    const float* __restrict__ Wm2,
    float* __restrict__ Wt1, float* __restrict__ Wt2, float* __restrict__ Wt3,
    float* __restrict__ bias1, float* __restrict__ bias2,
    float* __restrict__ bias3, float* __restrict__ BT,
    __half* __restrict__ W2B) {
  int idx = blockIdx.x * 256 + threadIdx.x;
  if (idx < 16384) {  // Wt1 [128k x 128f] = [W1l | W1r]^T
    int k = idx >> 7, f = idx & 127;
    Wt1[idx] = (f < 64) ? W1l[f * 128 + k] : W1r[(f - 64) * 128 + k];
    return;
  }
  idx -= 16384;
  if (idx < 8192) {   // Wt2 [64k x 128f] = [W2l | W2r]^T
    int k = idx >> 7, f = idx & 127;
    Wt2[idx] = (f < 64) ? W2l[f * 64 + k] : W2r[(f - 64) * 64 + k];
    return;
  }
  idx -= 8192;
  if (idx < 16384) {  // Wt3 [64k x 256f] = [A1 | C1]^T  (col slices of Wm1)
    int k = idx >> 8, f = idx & 255;
    Wt3[idx] = (f < 128) ? Wm1[f * 144 + k] : Wm1[(f - 128) * 144 + 80 + k];
    return;
  }
  idx -= 16384;
  if (idx < 128) { bias1[idx] = (idx < 64) ? 0.f : b1l[idx - 64]; return; }
  idx -= 128;
  if (idx < 128) { bias2[idx] = (idx < 64) ? 0.f : b2l[idx - 64]; return; }
  idx -= 128;
  if (idx < 256) { bias3[idx] = (idx < 128) ? bm1[idx] : 0.f; return; }
  idx -= 256;
  if (idx < 2048) {   // BT [16k x 128c] = attr-slice of Wm1, fp32
    int k = idx >> 7, c = idx & 127;
    BT[idx] = Wm1[c * 144 + 64 + k];
    return;
  }
  idx -= 2048;
  if (idx < 8192) {   // W2B: Wm2^T pre-swizzled to MFMA B-fragment layout
    // frag f = kc*4 + t ; lane l ; elem j:  B[k][col], col=16t+(l&15),
    // k = 32*kc + (l>>4)*8 + j
    int j = idx & 7, l = (idx >> 3) & 63, f = idx >> 9;
    int kc = f >> 2, tt = f & 3;
    int col = 16 * tt + (l & 15);
    int k = 32 * kc + (l >> 4) * 8 + j;
    W2B[idx] = __float2half(Wm2[col * 128 + k]);
    return;
  }
}

// ---------------- register-blocked node GEMM ----------------
// acc[n][f] = bias[f] + sum_k Xeff[n][k] * Wt[k*Ftot+f], f in [0,128)
// Xeff = stats ? relu(X*sc+sh) : X.  Tile 64n x 128f, BK=32, 4x8 acc/thread.
// MODE 0: cols 0-63 -> half outH (stride 64), 64-127 -> float outF (stride 64)
// MODE 1: all 128 cols -> half outH (stride 128)
// MODE 2: all 128 cols -> float outF (stride 128)
template<int K, int MODE>
__global__ __launch_bounds__(256) void k_gemm(
    const float* __restrict__ X, const float* __restrict__ stats,
    const float* __restrict__ Wt, const float* __restrict__ bias,
    __half* __restrict__ outH, float* __restrict__ outF, int N, int Ftot) {
  __shared__ __align__(16) float Xs[32][68];
  __shared__ __align__(16) float Ws_[32][128];
  const int tid = threadIdx.x;
  const int tx  = tid & 15;
  const int ty  = tid >> 4;
  const int n0  = blockIdx.x * 64;
  float acc[4][8];
#pragma unroll
  for (int j = 0; j < 8; ++j) {
    float bv = bias[8 * tx + j];
#pragma unroll
    for (int i = 0; i < 4; ++i) acc[i][j] = bv;
  }
  for (int k0 = 0; k0 < K; k0 += 32) {
    __syncthreads();
#pragma unroll
    for (int l = 0; l < 2; ++l) {
      int idx = tid * 2 + l;
      int kq = idx & 7, n = idx >> 3;
      float4 xv = make_float4(0.f, 0.f, 0.f, 0.f);
      if (n0 + n < N) xv = *(const float4*)&X[(size_t)(n0 + n) * K + k0 + kq * 4];
      if (stats) {
        int kb = k0 + kq * 4;
        xv.x = fmaxf(xv.x * stats[128 + kb + 0] + stats[192 + kb + 0], 0.f);
        xv.y = fmaxf(xv.y * stats[128 + kb + 1] + stats[192 + kb + 1], 0.f);
        xv.z = fmaxf(xv.z * stats[128 + kb + 2] + stats[192 + kb + 2], 0.f);
        xv.w = fmaxf(xv.w * stats[128 + kb + 3] + stats[192 + kb + 3], 0.f);
      }
      Xs[kq * 4 + 0][n] = xv.x;
      Xs[kq * 4 + 1][n] = xv.y;
      Xs[kq * 4 + 2][n] = xv.z;
      Xs[kq * 4 + 3][n] = xv.w;
    }
#pragma unroll
    for (int l = 0; l < 4; ++l) {
      int idx = tid + l * 256;
      int kr = idx >> 5, fc = idx & 31;
      *(float4*)&Ws_[kr][fc * 4] =
          *(const float4*)&Wt[(size_t)(k0 + kr) * Ftot + fc * 4];
    }
    __syncthreads();
#pragma unroll
    for (int kk = 0; kk < 32; ++kk) {
      float4 a  = *(const float4*)&Xs[kk][4 * ty];
      float4 b0 = *(const float4*)&Ws_[kk][8 * tx];
      float4 b1 = *(const float4*)&Ws_[kk][8 * tx + 4];
      float aa[4] = {a.x, a.y, a.z, a.w};
      float bb[8] = {b0.x, b0.y, b0.z, b0.w, b1.x, b1.y, b1.z, b1.w};
#pragma unroll
      for (int i = 0; i < 4; ++i)
#pragma unroll
        for (int j = 0; j < 8; ++j) acc[i][j] += aa[i] * bb[j];
    }
  }
#pragma unroll
  for (int i = 0; i < 4; ++i) {
    int n = n0 + 4 * ty + i;
    if (n >= N) continue;
    if constexpr (MODE == 0) {
      if (tx < 8) {
        __half2 hh[4];
#pragma unroll
        for (int c = 0; c < 4; ++c)
          hh[c] = __floats2half2_rn(acc[i][2 * c], acc[i][2 * c + 1]);
        *(uint4*)&outH[(size_t)n * 64 + 8 * tx] = *(uint4*)hh;
      } else {
        float* cp = outF + (size_t)n * 64 + 8 * tx - 64;
        *(float4*)cp = make_float4(acc[i][0], acc[i][1], acc[i][2], acc[i][3]);
        *(float4*)(cp + 4) = make_float4(acc[i][4], acc[i][5], acc[i][6], acc[i][7]);
      }
    } else if constexpr (MODE == 1) {
      __half2 hh[4];
#pragma unroll
      for (int c = 0; c < 4; ++c)
        hh[c] = __floats2half2_rn(acc[i][2 * c], acc[i][2 * c + 1]);
      *(uint4*)&outH[(size_t)n * 128 + 8 * tx] = *(uint4*)hh;
    } else {
      float* cp = outF + (size_t)n * 128 + 8 * tx;
      *(float4*)cp = make_float4(acc[i][0], acc[i][1], acc[i][2], acc[i][3]);
      *(float4*)(cp + 4) = make_float4(acc[i][4], acc[i][5], acc[i][6], acc[i][7]);
    }
  }
}

// ---------------- fused aggregate + mean + residual + BN stats ----------------
__global__ __launch_bounds__(256) void k_agg(
    const __half* __restrict__ qb, const float* __restrict__ pb,
    const int* __restrict__ rowptr, const int* __restrict__ csr_src,
    float* __restrict__ hpre, float* __restrict__ stats, int N) {
  __shared__ float red[512];
  const int f  = threadIdx.x & 63;
  const int ns = threadIdx.x >> 6;
  float lsum = 0.f, lsq = 0.f;
  for (int n = blockIdx.x * 4 + ns; n < N; n += gridDim.x * 4) {
    const int r0 = rowptr[n], r1 = rowptr[n + 1];
    float s0 = 0.f, s1 = 0.f, s2 = 0.f, s3 = 0.f;
    int j = r0;
    for (; j + 3 < r1; j += 4) {
      int a0 = csr_src[j], a1 = csr_src[j + 1];
      int a2 = csr_src[j + 2], a3 = csr_src[j + 3];
      s0 += __half2float(qb[(size_t)a0 * 64 + f]);
      s1 += __half2float(qb[(size_t)a1 * 64 + f]);
      s2 += __half2float(qb[(size_t)a2 * 64 + f]);
      s3 += __half2float(qb[(size_t)a3 * 64 + f]);
    }
    for (; j < r1; ++j) s0 += __half2float(qb[(size_t)csr_src[j] * 64 + f]);
    float c = (float)(r1 - r0);
    c = c > 1.f ? c : 1.f;
    float v = ((s0 + s1) + (s2 + s3)) / c + pb[(size_t)n * 64 + f];
    hpre[(size_t)n * 64 + f] = v;
    lsum += v;
    lsq  += v * v;
  }
  red[threadIdx.x]       = lsum;
  red[256 + threadIdx.x] = lsq;
  __syncthreads();
  if (threadIdx.x < 64) {
    float ts = red[f] + red[f + 64] + red[f + 128] + red[f + 192];
    float tq = red[256 + f] + red[256 + f + 64] + red[256 + f + 128] + red[256 + f + 192];
    atomicAdd(&stats[f], ts);
    atomicAdd(&stats[64 + f], tq);
  }
}

// stats -> BN scale/shift: sc=g*invstd, sh=be-mean*sc
__global__ void k_finalize(float* stats, const float* __restrict__ g,
                           const float* __restrict__ be, int N) {
  int f = threadIdx.x;  // 64 threads
  float inv_n = 1.0f / (float)N;
  float mean = stats[f] * inv_n;
  float var  = stats[64 + f] * inv_n - mean * mean;
  float s = g[f] * rsqrtf(var + EPS);
  stats[128 + f] = s;
  stats[192 + f] = be[f] - mean * s;
}

// ---------------------------------------------------------------------------
// Fused edge MLP, dst-CSR order, MFMA layer 2. Per 64-edge tile:
//   z1[e][c] = relu(u16[csrc[e]][c] + v[cdst[e]][c] + attr[ceid[e]]·BT[:,c])
//   z2 = relu(z1 @ W2T + bm2)  -- 16x16x32_f16 MFMA, 16/wave/tile
//   out[ceid[e]] = z2 @ Wm3.T + bm3  -- shfl-reduced from C-layout accs
// LDS = 17408(Z1) + 16384(W2B) + 4096(attr) + 768(idx/eid) = 38656 B -> 4/CU.
// ---------------------------------------------------------------------------
__global__ __launch_bounds__(256, 4) void k_edge(
    const __half* __restrict__ U16, const float* __restrict__ V32,
    const float* __restrict__ attr,
    const int* __restrict__ csrc, const int* __restrict__ cdst,
    const int* __restrict__ ceid,
    const __half* __restrict__ W2Bws, const float* __restrict__ BTws,
    const float* __restrict__ bm2, const float* __restrict__ Wm3,
    const float* __restrict__ bm3, float* __restrict__ out, int E) {
  __shared__ __align__(16) _Float16 Z1f[64 * 136];   // [e][c] pad 128->136
  __shared__ __align__(16) _Float16 W2B[8192];       // B-fragment layout
  __shared__ __align__(16) float attrL[64 * 16];
  __shared__ int idxL[128];                          // src | dst
  __shared__ int eidL[64];

  const int tid  = threadIdx.x;
  const int c4   = tid & 31;
  const int lane = tid & 63;
  const int w    = tid >> 6;
  const int ln15 = lane & 15;
  const int quad = lane >> 4;

  for (int i = tid; i < 1024; i += 256)
    ((uint4*)W2B)[i] = ((const uint4*)W2Bws)[i];

  // per-lane constants (C layout: col = 16*t + ln15)
  float bmv[4], w30[4], w31[4];
#pragma unroll
  for (int t = 0; t < 4; ++t) {
    bmv[t] = bm2[16 * t + ln15];
    w30[t] = Wm3[16 * t + ln15];
    w31[t] = Wm3[64 + 16 * t + ln15];
  }
  const float bm30 = bm3[0], bm31 = bm3[1];

  const __half2* uh2 = (const __half2*)U16;  // 64 half2 per node row
  const float4*  v4  = (const float4*)V32;   // 32 float4 per node row
  const float4*  at4 = (const float4*)attr;
  const float4*  bt4 = (const float4*)BTws;

  const int nt = (E + 63) >> 6;
  for (int t = blockIdx.x; t < nt; t += gridDim.x) {
    const int e0 = t << 6;
    __syncthreads();   // protect Z1/idx/attr vs previous tile (+W2B staging)

    if (tid < 64) {
      int j = e0 + tid;
      idxL[tid]      = (j < E) ? csrc[j] : 0;
      idxL[64 + tid] = (j < E) ? cdst[j] : 0;
      eidL[tid]      = (j < E) ? ceid[j] : -1;
    }
    float4 breg[16];
#pragma unroll
    for (int k = 0; k < 16; ++k) breg[k] = bt4[k * 32 + c4];  // L1-hot
    __syncthreads();

    {  // attr gather by original edge id
      int e = tid >> 2, k4 = tid & 3;
      int eid = eidL[e];
      float4 av = make_float4(0.f, 0.f, 0.f, 0.f);
      if (eid >= 0) av = at4[(size_t)eid * 4 + k4];
      ((float4*)attrL)[tid] = av;
    }
    __syncthreads();

    // ---- layer 1: 64 edges x 32 col-chunks of 4, fp16 u + fp32 v ----
#pragma unroll
    for (int it = 0; it < 8; ++it) {
      const int e = it * 8 + (tid >> 5);
      uint2 ur = *(const uint2*)&uh2[(size_t)idxL[e] * 64 + 2 * c4];
      float2 u01 = __half22float2(*reinterpret_cast<__half2*>(&ur.x));
      float2 u23 = __half22float2(*reinterpret_cast<__half2*>(&ur.y));
      float4 b = v4[(size_t)idxL[64 + e] * 32 + c4];
      float sx = u01.x + b.x, sy = u01.y + b.y;
      float sz = u23.x + b.z, sw = u23.y + b.w;
#pragma unroll
      for (int k = 0; k < 16; ++k) {
        float av = attrL[e * 16 + k];
        sx += av * breg[k].x; sy += av * breg[k].y;
        sz += av * breg[k].z; sw += av * breg[k].w;
      }
      __half2* zp = (__half2*)&Z1f[e * 136 + 4 * c4];
      zp[0] = __floats2half2_rn(fmaxf(sx, 0.f), fmaxf(sy, 0.f));
      zp[1] = __floats2half2_rn(fmaxf(sz, 0.f), fmaxf(sw, 0.f));
    }
    __syncthreads();

    // ---- layer 2: MFMA. wave w: edges 16w..16w+15, all 64 cols ----
    f32x4 acc[4];
#pragma unroll
    for (int tt = 0; tt < 4; ++tt)
      acc[tt] = (f32x4){bmv[tt], bmv[tt], bmv[tt], bmv[tt]};
#pragma unroll
    for (int kc = 0; kc < 4; ++kc) {
      h8 a = *(const h8*)&Z1f[(16 * w + ln15) * 136 + 32 * kc + 8 * quad];
#pragma unroll
      for (int tt = 0; tt < 4; ++tt) {
        h8 bf = *(const h8*)&W2B[((kc * 4 + tt) * 64 + lane) * 8];
        acc[tt] = __builtin_amdgcn_mfma_f32_16x16x32_f16(a, bf, acc[tt], 0, 0, 0);
      }
    }

    // ---- layer 3: relu + dot Wm3, reduce 16 cols/lane-group via shfl ----
    float p0[4], p1[4];
#pragma unroll
    for (int r = 0; r < 4; ++r) { p0[r] = 0.f; p1[r] = 0.f; }
#pragma unroll
    for (int tt = 0; tt < 4; ++tt)
#pragma unroll
      for (int r = 0; r < 4; ++r) {
        float z = fmaxf(acc[tt][r], 0.f);
        p0[r] += z * w30[tt];
        p1[r] += z * w31[tt];
      }
#pragma unroll
    for (int r = 0; r < 4; ++r) {
#pragma unroll
      for (int m = 1; m < 16; m <<= 1) {
        p0[r] += __shfl_xor(p0[r], m);
        p1[r] += __shfl_xor(p1[r], m);
      }
      if (ln15 == 0) {
        int e = 16 * w + 4 * quad + r;   // C row = quad*4 + reg
        int eid = eidL[e];
        if (eid >= 0)
          *(float2*)&out[(size_t)eid * 2] = make_float2(p0[r] + bm30, p1[r] + bm31);
      }
    }
  }
}

extern "C" void kernel_launch(void* const* d_in, const int* in_sizes, int n_in,
                              void* d_out, int out_size, void* d_ws, size_t ws_size,
                              hipStream_t stream) {
  const float* x    = (const float*)d_in[0];
  const int*   ei   = (const int*)d_in[1];
  const float* attr = (const float*)d_in[2];
  const float* W1l  = (const float*)d_in[3];
  const float* b1l  = (const float*)d_in[4];
  const float* W1r  = (const float*)d_in[5];
  const float* g1   = (const float*)d_in[6];
  const float* be1  = (const float*)d_in[7];
  const float* W2l  = (const float*)d_in[8];
  const float* b2l  = (const float*)d_in[9];
  const float* W2r  = (const float*)d_in[10];
  const float* g2   = (const float*)d_in[11];
  const float* be2  = (const float*)d_in[12];
  const float* Wm1  = (const float*)d_in[13];
  const float* bm1  = (const float*)d_in[14];
  const float* Wm2  = (const float*)d_in[15];
  const float* bm2  = (const float*)d_in[16];
  const float* Wm3  = (const float*)d_in[17];
  const float* bm3  = (const float*)d_in[18];
  float* out = (float*)d_out;

  const int N = in_sizes[0] / 128;
  const int E = in_sizes[1] / 2;
  const int* srcI = ei;
  const int* dstI = ei + E;

  float* ws = (float*)d_ws;
  const size_t NF = (size_t)N * 64;
  float*  P32 = ws;                        // [N][64] f32
  float*  H1  = ws + NF;                   // [N][64] f32 (reused as H2)
  float*  V32 = ws + 2 * NF;               // [N][128] f32
  __half* Q16 = (__half*)(ws + 4 * NF);    // [N][64] f16
  __half* U16 = (__half*)(ws + 4 * NF + NF / 2);  // [N][128] f16
  float* small  = ws + 5 * NF + NF / 2;
  float* stats1 = small;          // 256
  float* stats2 = stats1 + 256;   // 256
  float* Wt1    = stats2 + 256;   // 128*128
  float* Wt2    = Wt1 + 16384;    // 64*128
  float* Wt3    = Wt2 + 8192;     // 64*256
  float* bias1  = Wt3 + 16384;    // 128
  float* bias2  = bias1 + 128;    // 128
  float* bias3  = bias2 + 128;    // 256
  float* BTws   = bias3 + 256;    // 16*128
  __half* W2B   = (__half*)(BTws + 2048);   // 8192 halfs = 4096 floats
  int* rowptr = (int*)(BTws + 2048 + 4096); // N+1
  int* cursor = rowptr + (N + 1);           // N
  int* deg    = cursor + N;                 // N
  int* csrsrc = deg + N;                    // E
  int* csrdst = csrsrc + E;                 // E
  int* csreid = csrdst + E;                 // E

  hipMemsetAsync(deg, 0, (size_t)N * sizeof(int), stream);
  hipMemsetAsync(stats1, 0, 512 * sizeof(float), stream);

  // ---- CSR build + weight prep ----
  const int eBlocks = (E + 255) / 256;
  k_hist<<<eBlocks, 256, 0, stream>>>(dstI, deg, E);
  k_scan<<<1, 1024, 0, stream>>>(deg, rowptr, cursor, N);
  k_fill<<<eBlocks, 256, 0, stream>>>(srcI, dstI, cursor, csrsrc, csrdst, csreid, E);
  k_prep<<<(51712 + 255) / 256, 256, 0, stream>>>(
      W1l, W1r, b1l, W2l, W2r, b2l, Wm1, bm1, Wm2,
      Wt1, Wt2, Wt3, bias1, bias2, bias3, BTws, W2B);

  const int mTiles = (N + 63) / 64;

  // ---- conv1: Q16 = fp16(x@W1l^T), P32 = x@W1r^T + b1l ----
  k_gemm<128, 0><<<mTiles, 256, 0, stream>>>(x, nullptr, Wt1, bias1, Q16, P32, N, 128);
  k_agg<<<1024, 256, 0, stream>>>(Q16, P32, rowptr, csrsrc, H1, stats1, N);
  k_finalize<<<1, 64, 0, stream>>>(stats1, g1, be1, N);

  // ---- conv2 (BN1+relu fused into GEMM input) ----
  k_gemm<64, 0><<<mTiles, 256, 0, stream>>>(H1, stats1, Wt2, bias2, Q16, P32, N, 128);
  k_agg<<<1024, 256, 0, stream>>>(Q16, P32, rowptr, csrsrc, H1, stats2, N);  // H2=H1
  k_finalize<<<1, 64, 0, stream>>>(stats2, g2, be2, N);

  // ---- U16 = fp16(h2@A1^T + bm1), V32 = h2@C1^T (BN2+relu fused) ----
  k_gemm<64, 1><<<mTiles, 256, 0, stream>>>(H1, stats2, Wt3, bias3, U16, nullptr, N, 256);
  k_gemm<64, 2><<<mTiles, 256, 0, stream>>>(H1, stats2, Wt3 + 128, bias3 + 128,
                                            nullptr, V32, N, 256);

  // ---- fused edge MLP over dst-ordered edges (MFMA layer 2) ----
  k_edge<<<1024, 256, 0, stream>>>(U16, V32, attr, csrsrc, csrdst, csreid,
                                   W2B, BTws, bm2, Wm3, bm3, out, E);
}

// Round 9
// 643.720 us; speedup vs baseline: 1.5743x; 1.0736x over previous
//
#include <hip/hip_runtime.h>
#include <hip/hip_fp16.h>

// ---------------------------------------------------------------------------
// EdgeClassifierGNN: 2x SAGEConv(mean)+BN+ReLU, then 3-layer edge MLP.
// Trick 1: lin_l before mean-aggregation (64-wide gather).
// Trick 2: edge-MLP layer 1 split: z1 = relu(u[src] + v[dst] + B1*attr).
// Trick 3: CSR by dst -> atomic-free aggregation; k_edge in dst order.
// Trick 4: node linears via register-blocked GEMM, BN fused on input.
// Trick 5: random-gather tables in fp16 (q 6.4 MB, u 12.8 MB).
// Trick 6: k_edge layer 2 via v_mfma_f32_16x16x32_f16 + shfl epilogue.
// Trick 7 (r9): k_agg wave-per-node with 8-edges-per-load gather (1 KB per
//          load instr vs 128 B) + butterfly reduce — kills the serialized
//          narrow-gather latency. UV GEMMs merged; prep merged into hist.
// ---------------------------------------------------------------------------

#define EPS 1e-5f

typedef _Float16 h8 __attribute__((ext_vector_type(8)));
typedef float f32x4 __attribute__((ext_vector_type(4)));

// ---------------- CSR build + weight prep (merged) ----------------
__global__ __launch_bounds__(256) void k_prep_hist(
    const float* __restrict__ W1l, const float* __restrict__ W1r,
    const float* __restrict__ b1l,
    const float* __restrict__ W2l, const float* __restrict__ W2r,
    const float* __restrict__ b2l,
    const float* __restrict__ Wm1, const float* __restrict__ bm1,
    const float* __restrict__ Wm2,
    float* __restrict__ Wt1, float* __restrict__ Wt2, float* __restrict__ Wt3,
    float* __restrict__ bias1, float* __restrict__ bias2,
    float* __restrict__ bias3, float* __restrict__ BT,
    __half* __restrict__ W2B,
    const int* __restrict__ dst, int* __restrict__ deg, int E, int prepBlocks) {
  if ((int)blockIdx.x >= prepBlocks) {
    int e = (blockIdx.x - prepBlocks) * 256 + threadIdx.x;
    if (e < E) atomicAdd(&deg[dst[e]], 1);
    return;
  }
  int idx = blockIdx.x * 256 + threadIdx.x;
  if (idx < 16384) {  // Wt1 [128k x 128f] = [W1l | W1r]^T
    int k = idx >> 7, f = idx & 127;
    Wt1[idx] = (f < 64) ? W1l[f * 128 + k] : W1r[(f - 64) * 128 + k];
    return;
  }
  idx -= 16384;
  if (idx < 8192) {   // Wt2 [64k x 128f] = [W2l | W2r]^T
    int k = idx >> 7, f = idx & 127;
    Wt2[idx] = (f < 64) ? W2l[f * 64 + k] : W2r[(f - 64) * 64 + k];
    return;
  }
  idx -= 8192;
  if (idx < 16384) {  // Wt3 [64k x 256f] = [A1 | C1]^T  (col slices of Wm1)
    int k = idx >> 8, f = idx & 255;
    Wt3[idx] = (f < 128) ? Wm1[f * 144 + k] : Wm1[(f - 128) * 144 + 80 + k];
    return;
  }
  idx -= 16384;
  if (idx < 128) { bias1[idx] = (idx < 64) ? 0.f : b1l[idx - 64]; return; }
  idx -= 128;
  if (idx < 128) { bias2[idx] = (idx < 64) ? 0.f : b2l[idx - 64]; return; }
  idx -= 128;
  if (idx < 256) { bias3[idx] = (idx < 128) ? bm1[idx] : 0.f; return; }
  idx -= 256;
  if (idx < 2048) {   // BT [16k x 128c] = attr-slice of Wm1, fp32
    int k = idx >> 7, c = idx & 127;
    BT[idx] = Wm1[c * 144 + 64 + k];
    return;
  }
  idx -= 2048;
  if (idx < 8192) {   // W2B: Wm2^T pre-swizzled to MFMA B-fragment layout
    int j = idx & 7, l = (idx >> 3) & 63, f = idx >> 9;
    int kc = f >> 2, tt = f & 3;
    int col = 16 * tt + (l & 15);
    int k = 32 * kc + (l >> 4) * 8 + j;
    W2B[idx] = __float2half(Wm2[col * 128 + k]);
    return;
  }
}

__global__ __launch_bounds__(1024) void k_scan(
    const int* __restrict__ deg, int* __restrict__ rowptr,
    int* __restrict__ cursor, int N) {
  __shared__ int wsum[16];
  __shared__ int carry;
  const int lane = threadIdx.x & 63;
  const int w    = threadIdx.x >> 6;
  if (threadIdx.x == 0) carry = 0;
  __syncthreads();
  for (int base = 0; base < N; base += 1024) {
    int i = base + threadIdx.x;
    int v = (i < N) ? deg[i] : 0;
    int incl = v;
#pragma unroll
    for (int off = 1; off < 64; off <<= 1) {
      int t = __shfl_up(incl, off);
      if (lane >= off) incl += t;
    }
    if (lane == 63) wsum[w] = incl;
    __syncthreads();
    if (w == 0) {
      int ws_ = (lane < 16) ? wsum[lane] : 0;
      int wincl = ws_;
#pragma unroll
      for (int off = 1; off < 16; off <<= 1) {
        int t = __shfl_up(wincl, off);
        if (lane >= off) wincl += t;
      }
      if (lane < 16) wsum[lane] = wincl;
    }
    __syncthreads();
    int woff = carry + (w > 0 ? wsum[w - 1] : 0);
    int excl = woff + incl - v;
    if (i < N) { rowptr[i] = excl; cursor[i] = excl; }
    int tot = wsum[15];
    __syncthreads();
    if (threadIdx.x == 0) carry += tot;
    __syncthreads();
  }
  if (threadIdx.x == 0) rowptr[N] = carry;
}

__global__ __launch_bounds__(256) void k_fill(
    const int* __restrict__ src, const int* __restrict__ dst,
    int* __restrict__ cursor, int* __restrict__ csr_src,
    int* __restrict__ csr_dst, int* __restrict__ csr_eid, int E) {
  int e = blockIdx.x * 256 + threadIdx.x;
  if (e < E) {
    int d = dst[e];
    int pos = atomicAdd(&cursor[d], 1);
    csr_src[pos] = src[e];
    csr_dst[pos] = d;
    csr_eid[pos] = e;
  }
}

// ---------------- register-blocked node GEMM ----------------
// MODE 0: cols 0-63 -> half outH (stride 64), 64-127 -> float outF (stride 64)
// MODE 3: blockIdx.y==0 -> half outH (stride 128); ==1 -> float outF, using
//         Wt+128/bias+128 (the V slice of the 256-wide concat).
template<int K, int MODE>
__global__ __launch_bounds__(256) void k_gemm(
    const float* __restrict__ X, const float* __restrict__ stats,
    const float* __restrict__ Wt, const float* __restrict__ bias,
    __half* __restrict__ outH, float* __restrict__ outF, int N, int Ftot) {
  __shared__ __align__(16) float Xs[32][68];
  __shared__ __align__(16) float Ws_[32][128];
  const int tid = threadIdx.x;
  const int tx  = tid & 15;
  const int ty  = tid >> 4;
  const int n0  = blockIdx.x * 64;
  int half2nd = 0;
  if constexpr (MODE == 3) half2nd = blockIdx.y;
  const float* WtB   = Wt + (half2nd ? 128 : 0);
  const float* biasB = bias + (half2nd ? 128 : 0);
  float acc[4][8];
#pragma unroll
  for (int j = 0; j < 8; ++j) {
    float bv = biasB[8 * tx + j];
#pragma unroll
    for (int i = 0; i < 4; ++i) acc[i][j] = bv;
  }
  for (int k0 = 0; k0 < K; k0 += 32) {
    __syncthreads();
#pragma unroll
    for (int l = 0; l < 2; ++l) {
      int idx = tid * 2 + l;
      int kq = idx & 7, n = idx >> 3;
      float4 xv = make_float4(0.f, 0.f, 0.f, 0.f);
      if (n0 + n < N) xv = *(const float4*)&X[(size_t)(n0 + n) * K + k0 + kq * 4];
      if (stats) {
        int kb = k0 + kq * 4;
        xv.x = fmaxf(xv.x * stats[128 + kb + 0] + stats[192 + kb + 0], 0.f);
        xv.y = fmaxf(xv.y * stats[128 + kb + 1] + stats[192 + kb + 1], 0.f);
        xv.z = fmaxf(xv.z * stats[128 + kb + 2] + stats[192 + kb + 2], 0.f);
        xv.w = fmaxf(xv.w * stats[128 + kb + 3] + stats[192 + kb + 3], 0.f);
      }
      Xs[kq * 4 + 0][n] = xv.x;
      Xs[kq * 4 + 1][n] = xv.y;
      Xs[kq * 4 + 2][n] = xv.z;
      Xs[kq * 4 + 3][n] = xv.w;
    }
#pragma unroll
    for (int l = 0; l < 4; ++l) {
      int idx = tid + l * 256;
      int kr = idx >> 5, fc = idx & 31;
      *(float4*)&Ws_[kr][fc * 4] =
          *(const float4*)&WtB[(size_t)(k0 + kr) * Ftot + fc * 4];
    }
    __syncthreads();
#pragma unroll
    for (int kk = 0; kk < 32; ++kk) {
      float4 a  = *(const float4*)&Xs[kk][4 * ty];
      float4 b0 = *(const float4*)&Ws_[kk][8 * tx];
      float4 b1 = *(const float4*)&Ws_[kk][8 * tx + 4];
      float aa[4] = {a.x, a.y, a.z, a.w};
      float bb[8] = {b0.x, b0.y, b0.z, b0.w, b1.x, b1.y, b1.z, b1.w};
#pragma unroll
      for (int i = 0; i < 4; ++i)
#pragma unroll
        for (int j = 0; j < 8; ++j) acc[i][j] += aa[i] * bb[j];
    }
  }
#pragma unroll
  for (int i = 0; i < 4; ++i) {
    int n = n0 + 4 * ty + i;
    if (n >= N) continue;
    if constexpr (MODE == 0) {
      if (tx < 8) {
        __half2 hh[4];
#pragma unroll
        for (int c = 0; c < 4; ++c)
          hh[c] = __floats2half2_rn(acc[i][2 * c], acc[i][2 * c + 1]);
        *(uint4*)&outH[(size_t)n * 64 + 8 * tx] = *(uint4*)hh;
      } else {
        float* cp = outF + (size_t)n * 64 + 8 * tx - 64;
        *(float4*)cp = make_float4(acc[i][0], acc[i][1], acc[i][2], acc[i][3]);
        *(float4*)(cp + 4) = make_float4(acc[i][4], acc[i][5], acc[i][6], acc[i][7]);
      }
    } else {  // MODE 3
      if (!half2nd) {
        __half2 hh[4];
#pragma unroll
        for (int c = 0; c < 4; ++c)
          hh[c] = __floats2half2_rn(acc[i][2 * c], acc[i][2 * c + 1]);
        *(uint4*)&outH[(size_t)n * 128 + 8 * tx] = *(uint4*)hh;
      } else {
        float* cp = outF + (size_t)n * 128 + 8 * tx;
        *(float4*)cp = make_float4(acc[i][0], acc[i][1], acc[i][2], acc[i][3]);
        *(float4*)(cp + 4) = make_float4(acc[i][4], acc[i][5], acc[i][6], acc[i][7]);
      }
    }
  }
}

// ---------------- fused aggregate + mean + residual + BN stats ----------------
// Wave-per-node. Lanes = 8 edge-groups (g=lane>>3) x 8 feature-octets (c=lane&7).
// One uint4 load per lane = 8 edges x 128 B per wave-instruction.
__global__ __launch_bounds__(256) void k_agg(
    const __half* __restrict__ qb, const float* __restrict__ pb,
    const int* __restrict__ rowptr, const int* __restrict__ csr_src,
    float* __restrict__ hpre, float* __restrict__ stats, int N) {
  __shared__ float red[512];
  const int tid  = threadIdx.x;
  const int w    = tid >> 6;
  const int lane = tid & 63;
  const int g    = lane >> 3, c = lane & 7;
  float lsum = 0.f, lsq = 0.f;
  const int wid = blockIdx.x * 4 + w;
  const int nw  = gridDim.x * 4;
  for (int n = wid; n < N; n += nw) {
    const int r0 = rowptr[n], r1 = rowptr[n + 1];
    float s[8] = {0.f, 0.f, 0.f, 0.f, 0.f, 0.f, 0.f, 0.f};
    for (int j = r0 + g; j < r1; j += 8) {
      int a = csr_src[j];
      uint4 rv = *(const uint4*)&qb[(size_t)a * 64 + 8 * c];
      const __half2* hp = (const __half2*)&rv;
#pragma unroll
      for (int q = 0; q < 4; ++q) {
        float2 f2 = __half22float2(hp[q]);
        s[2 * q]     += f2.x;
        s[2 * q + 1] += f2.y;
      }
    }
    // butterfly over the g bits (lane bits 3,4,5)
#pragma unroll
    for (int m = 8; m < 64; m <<= 1)
#pragma unroll
      for (int q = 0; q < 8; ++q) s[q] += __shfl_xor(s[q], m);
    // lane (g,c) finalizes feature f = 8c + g
    float sv = s[0];
#pragma unroll
    for (int q = 1; q < 8; ++q) sv = (g == q) ? s[q] : sv;
    float cdeg = (float)(r1 - r0);
    cdeg = cdeg > 1.f ? cdeg : 1.f;
    const int f = 8 * c + g;
    float v = sv / cdeg + pb[(size_t)n * 64 + f];
    hpre[(size_t)n * 64 + f] = v;
    lsum += v;
    lsq  += v * v;
  }
  red[tid]       = lsum;
  red[256 + tid] = lsq;
  __syncthreads();
  if (tid < 64) {  // same lane->feature map in every wave
    float ts = red[tid] + red[tid + 64] + red[tid + 128] + red[tid + 192];
    float tq = red[256 + tid] + red[256 + tid + 64] + red[256 + tid + 128] + red[256 + tid + 192];
    int f = 8 * (tid & 7) + (tid >> 3);
    atomicAdd(&stats[f], ts);
    atomicAdd(&stats[64 + f], tq);
  }
}

// stats -> BN scale/shift: sc=g*invstd, sh=be-mean*sc
__global__ void k_finalize(float* stats, const float* __restrict__ g,
                           const float* __restrict__ be, int N) {
  int f = threadIdx.x;  // 64 threads
  float inv_n = 1.0f / (float)N;
  float mean = stats[f] * inv_n;
  float var  = stats[64 + f] * inv_n - mean * mean;
  float s = g[f] * rsqrtf(var + EPS);
  stats[128 + f] = s;
  stats[192 + f] = be[f] - mean * s;
}

// ---------------------------------------------------------------------------
// Fused edge MLP, dst-CSR order, MFMA layer 2 (unchanged from round 8).
// ---------------------------------------------------------------------------
__global__ __launch_bounds__(256, 4) void k_edge(
    const __half* __restrict__ U16, const float* __restrict__ V32,
    const float* __restrict__ attr,
    const int* __restrict__ csrc, const int* __restrict__ cdst,
    const int* __restrict__ ceid,
    const __half* __restrict__ W2Bws, const float* __restrict__ BTws,
    const float* __restrict__ bm2, const float* __restrict__ Wm3,
    const float* __restrict__ bm3, float* __restrict__ out, int E) {
  __shared__ __align__(16) _Float16 Z1f[64 * 136];
  __shared__ __align__(16) _Float16 W2B[8192];
  __shared__ __align__(16) float attrL[64 * 16];
  __shared__ int idxL[128];
  __shared__ int eidL[64];

  const int tid  = threadIdx.x;
  const int c4   = tid & 31;
  const int lane = tid & 63;
  const int w    = tid >> 6;
  const int ln15 = lane & 15;
  const int quad = lane >> 4;

  for (int i = tid; i < 1024; i += 256)
    ((uint4*)W2B)[i] = ((const uint4*)W2Bws)[i];

  float bmv[4], w30[4], w31[4];
#pragma unroll
  for (int t = 0; t < 4; ++t) {
    bmv[t] = bm2[16 * t + ln15];
    w30[t] = Wm3[16 * t + ln15];
    w31[t] = Wm3[64 + 16 * t + ln15];
  }
  const float bm30 = bm3[0], bm31 = bm3[1];

  const __half2* uh2 = (const __half2*)U16;
  const float4*  v4  = (const float4*)V32;
  const float4*  at4 = (const float4*)attr;
  const float4*  bt4 = (const float4*)BTws;

  const int nt = (E + 63) >> 6;
  for (int t = blockIdx.x; t < nt; t += gridDim.x) {
    const int e0 = t << 6;
    __syncthreads();

    if (tid < 64) {
      int j = e0 + tid;
      idxL[tid]      = (j < E) ? csrc[j] : 0;
      idxL[64 + tid] = (j < E) ? cdst[j] : 0;
      eidL[tid]      = (j < E) ? ceid[j] : -1;
    }
    float4 breg[16];
#pragma unroll
    for (int k = 0; k < 16; ++k) breg[k] = bt4[k * 32 + c4];
    __syncthreads();

    {
      int e = tid >> 2, k4 = tid & 3;
      int eid = eidL[e];
      float4 av = make_float4(0.f, 0.f, 0.f, 0.f);
      if (eid >= 0) av = at4[(size_t)eid * 4 + k4];
      ((float4*)attrL)[tid] = av;
    }
    __syncthreads();

#pragma unroll
    for (int it = 0; it < 8; ++it) {
      const int e = it * 8 + (tid >> 5);
      uint2 ur = *(const uint2*)&uh2[(size_t)idxL[e] * 64 + 2 * c4];
      float2 u01 = __half22float2(*reinterpret_cast<__half2*>(&ur.x));
      float2 u23 = __half22float2(*reinterpret_cast<__half2*>(&ur.y));
      float4 b = v4[(size_t)idxL[64 + e] * 32 + c4];
      float sx = u01.x + b.x, sy = u01.y + b.y;
      float sz = u23.x + b.z, sw = u23.y + b.w;
#pragma unroll
      for (int k = 0; k < 16; ++k) {
        float av = attrL[e * 16 + k];
        sx += av * breg[k].x; sy += av * breg[k].y;
        sz += av * breg[k].z; sw += av * breg[k].w;
      }
      __half2* zp = (__half2*)&Z1f[e * 136 + 4 * c4];
      zp[0] = __floats2half2_rn(fmaxf(sx, 0.f), fmaxf(sy, 0.f));
      zp[1] = __floats2half2_rn(fmaxf(sz, 0.f), fmaxf(sw, 0.f));
    }
    __syncthreads();

    f32x4 acc[4];
#pragma unroll
    for (int tt = 0; tt < 4; ++tt)
      acc[tt] = (f32x4){bmv[tt], bmv[tt], bmv[tt], bmv[tt]};
#pragma unroll
    for (int kc = 0; kc < 4; ++kc) {
      h8 a = *(const h8*)&Z1f[(16 * w + ln15) * 136 + 32 * kc + 8 * quad];
#pragma unroll
      for (int tt = 0; tt < 4; ++tt) {
        h8 bf = *(const h8*)&W2B[((kc * 4 + tt) * 64 + lane) * 8];
        acc[tt] = __builtin_amdgcn_mfma_f32_16x16x32_f16(a, bf, acc[tt], 0, 0, 0);
      }
    }

    float p0[4], p1[4];
#pragma unroll
    for (int r = 0; r < 4; ++r) { p0[r] = 0.f; p1[r] = 0.f; }
#pragma unroll
    for (int tt = 0; tt < 4; ++tt)
#pragma unroll
      for (int r = 0; r < 4; ++r) {
        float z = fmaxf(acc[tt][r], 0.f);
        p0[r] += z * w30[tt];
        p1[r] += z * w31[tt];
      }
#pragma unroll
    for (int r = 0; r < 4; ++r) {
#pragma unroll
      for (int m = 1; m < 16; m <<= 1) {
        p0[r] += __shfl_xor(p0[r], m);
        p1[r] += __shfl_xor(p1[r], m);
      }
      if (ln15 == 0) {
        int e = 16 * w + 4 * quad + r;
        int eid = eidL[e];
        if (eid >= 0)
          *(float2*)&out[(size_t)eid * 2] = make_float2(p0[r] + bm30, p1[r] + bm31);
      }
    }
  }
}

extern "C" void kernel_launch(void* const* d_in, const int* in_sizes, int n_in,
                              void* d_out, int out_size, void* d_ws, size_t ws_size,
                              hipStream_t stream) {
  const float* x    = (const float*)d_in[0];
  const int*   ei   = (const int*)d_in[1];
  const float* attr = (const float*)d_in[2];
  const float* W1l  = (const float*)d_in[3];
  const float* b1l  = (const float*)d_in[4];
  const float* W1r  = (const float*)d_in[5];
  const float* g1   = (const float*)d_in[6];
  const float* be1  = (const float*)d_in[7];
  const float* W2l  = (const float*)d_in[8];
  const float* b2l  = (const float*)d_in[9];
  const float* W2r  = (const float*)d_in[10];
  const float* g2   = (const float*)d_in[11];
  const float* be2  = (const float*)d_in[12];
  const float* Wm1  = (const float*)d_in[13];
  const float* bm1  = (const float*)d_in[14];
  const float* Wm2  = (const float*)d_in[15];
  const float* bm2  = (const float*)d_in[16];
  const float* Wm3  = (const float*)d_in[17];
  const float* bm3  = (const float*)d_in[18];
  float* out = (float*)d_out;

  const int N = in_sizes[0] / 128;
  const int E = in_sizes[1] / 2;
  const int* srcI = ei;
  const int* dstI = ei + E;

  float* ws = (float*)d_ws;
  const size_t NF = (size_t)N * 64;
  float*  P32 = ws;                        // [N][64] f32
  float*  H1  = ws + NF;                   // [N][64] f32 (reused as H2)
  float*  V32 = ws + 2 * NF;               // [N][128] f32
  __half* Q16 = (__half*)(ws + 4 * NF);    // [N][64] f16
  __half* U16 = (__half*)(ws + 4 * NF + NF / 2);  // [N][128] f16
  float* small  = ws + 5 * NF + NF / 2;
  float* stats1 = small;          // 256
  float* stats2 = stats1 + 256;   // 256
  float* Wt1    = stats2 + 256;   // 128*128
  float* Wt2    = Wt1 + 16384;    // 64*128
  float* Wt3    = Wt2 + 8192;     // 64*256
  float* bias1  = Wt3 + 16384;    // 128
  float* bias2  = bias1 + 128;    // 128
  float* bias3  = bias2 + 128;    // 256
  float* BTws   = bias3 + 256;    // 16*128
  __half* W2B   = (__half*)(BTws + 2048);   // 8192 halfs = 4096 floats
  int* rowptr = (int*)(BTws + 2048 + 4096); // N+1
  int* cursor = rowptr + (N + 1);           // N
  int* deg    = cursor + N;                 // N
  int* csrsrc = deg + N;                    // E
  int* csrdst = csrsrc + E;                 // E
  int* csreid = csrdst + E;                 // E

  hipMemsetAsync(deg, 0, (size_t)N * sizeof(int), stream);
  hipMemsetAsync(stats1, 0, 512 * sizeof(float), stream);

  // ---- weight prep + degree histogram (one launch) ----
  const int eBlocks = (E + 255) / 256;
  const int prepBlocks = (51712 + 255) / 256;
  k_prep_hist<<<prepBlocks + eBlocks, 256, 0, stream>>>(
      W1l, W1r, b1l, W2l, W2r, b2l, Wm1, bm1, Wm2,
      Wt1, Wt2, Wt3, bias1, bias2, bias3, BTws, W2B,
      dstI, deg, E, prepBlocks);
  k_scan<<<1, 1024, 0, stream>>>(deg, rowptr, cursor, N);
  k_fill<<<eBlocks, 256, 0, stream>>>(srcI, dstI, cursor, csrsrc, csrdst, csreid, E);

  const int mTiles = (N + 63) / 64;

  // ---- conv1: Q16 = fp16(x@W1l^T), P32 = x@W1r^T + b1l ----
  k_gemm<128, 0><<<mTiles, 256, 0, stream>>>(x, nullptr, Wt1, bias1, Q16, P32, N, 128);
  k_agg<<<1024, 256, 0, stream>>>(Q16, P32, rowptr, csrsrc, H1, stats1, N);
  k_finalize<<<1, 64, 0, stream>>>(stats1, g1, be1, N);

  // ---- conv2 (BN1+relu fused into GEMM input) ----
  k_gemm<64, 0><<<mTiles, 256, 0, stream>>>(H1, stats1, Wt2, bias2, Q16, P32, N, 128);
  k_agg<<<1024, 256, 0, stream>>>(Q16, P32, rowptr, csrsrc, H1, stats2, N);  // H2=H1
  k_finalize<<<1, 64, 0, stream>>>(stats2, g2, be2, N);

  // ---- U16 / V32 in one launch (BN2+relu fused) ----
  k_gemm<64, 3><<<dim3(mTiles, 2), 256, 0, stream>>>(H1, stats2, Wt3, bias3,
                                                     U16, V32, N, 256);

  // ---- fused edge MLP over dst-ordered edges (MFMA layer 2) ----
  k_edge<<<1024, 256, 0, stream>>>(U16, V32, attr, csrsrc, csrdst, csreid,
                                   W2B, BTws, bm2, Wm3, bm3, out, E);
}